// Round 1
// baseline (618.995 us; speedup 1.0000x reference)
//
#include <hip/hip_runtime.h>
#include <hip/hip_bf16.h>

#define H 1024
#define B 32
#define S 2048

typedef __attribute__((ext_vector_type(8))) short bf16x8;
typedef __attribute__((ext_vector_type(4))) float f32x4;

union U4 { uint4 u; bf16x8 b; };

__device__ __forceinline__ unsigned short f2bf(float f) {
    unsigned u = __float_as_uint(f);
    unsigned r = (u + 0x7fffu + ((u >> 16) & 1u)) >> 16;
    return (unsigned short)r;
}

__device__ __forceinline__ uint4 pack8(float4 x, float4 y) {
    uint4 p;
    p.x = (unsigned)f2bf(x.x) | ((unsigned)f2bf(x.y) << 16);
    p.y = (unsigned)f2bf(x.z) | ((unsigned)f2bf(x.w) << 16);
    p.z = (unsigned)f2bf(y.x) | ((unsigned)f2bf(y.y) << 16);
    p.w = (unsigned)f2bf(y.z) | ((unsigned)f2bf(y.w) << 16);
    return p;
}

__device__ __forceinline__ float ftanh(float x) {
    float x2 = __builtin_amdgcn_fmed3f(x + x, -30.f, 30.f);
    float e = __expf(x2);
    return 1.f - 2.f * __builtin_amdgcn_rcpf(e + 1.f);
}

__device__ __forceinline__ void async_copy16(const void* g, void* l) {
    __builtin_amdgcn_global_load_lds(
        (const __attribute__((address_space(1))) unsigned int*)g,
        (__attribute__((address_space(3))) unsigned int*)l, 16, 0, 0);
}

// ---------------------------------------------------------------------------
// K0: Ua_w fp32 [n][k] -> bf16 MFMA-B-frag order: UaSw[nb(8)][kc(32)][nt(8)*64+lane]
__global__ void k0_swizzle(const float* __restrict__ Ua, uint4* __restrict__ UaSw) {
    int t = blockIdx.x * 256 + threadIdx.x;   // 0..131071
    int lane = t & 63;
    int nt = (t >> 6) & 7;
    int kc = (t >> 9) & 31;
    int nb = t >> 14;
    int n = nb * 128 + nt * 16 + (lane & 15);
    int k = kc * 32 + ((lane >> 4) & 3) * 8;
    const float4* src = (const float4*)(Ua + (size_t)n * H + k);
    UaSw[t] = pack8(src[0], src[1]);
}

// ---------------------------------------------------------------------------
// KA: keys fp32 [b*S+s][h] -> bf16 MFMA A-frag order:
// Abf[g], g = (stile*32 + kc)*64 + lane; stile = (b*S+s)/16
// row = stile*16 + (lane&15); col = kc*32 + ((lane>>4)&3)*8 + j
__global__ __launch_bounds__(256) void ka_swz(const float* __restrict__ keys,
                                              uint4* __restrict__ Abf) {
    size_t g = (size_t)blockIdx.x * 256 + threadIdx.x;   // 0..8388607
    int lane = (int)(g & 63);
    size_t u = g >> 6;
    int kc = (int)(u & 31);
    size_t stile = u >> 5;                                // 0..4095
    size_t row = stile * 16 + (lane & 15);
    int col = kc * 32 + ((lane >> 4) & 3) * 8;
    const float4* src = (const float4*)(keys + row * H + col);
    Abf[g] = pack8(src[0], src[1]);
}

// ---------------------------------------------------------------------------
// K1: qp[b][n] = sum_h query[b][h]*Wa_w[n][h] + Wa_b[n] + Ua_b[n]
__global__ __launch_bounds__(256) void k1_qproj(
    const float* __restrict__ q, const float* __restrict__ Wa,
    const float* __restrict__ Wab, const float* __restrict__ Uab,
    float* __restrict__ qp) {
    int b = blockIdx.y;
    int t = threadIdx.x;
    int n = blockIdx.x * 64 + (t >> 2);
    int quarter = t & 3;
    __shared__ float qs[H];
    for (int i = t; i < H; i += 256) qs[i] = q[b * H + i];
    __syncthreads();
    const float4* wr = (const float4*)(Wa + (size_t)n * H + quarter * 256);
    const float* qq = qs + quarter * 256;
    float acc = 0.f;
#pragma unroll 4
    for (int i = 0; i < 64; i++) {
        float4 w = wr[i];
        acc += qq[i * 4 + 0] * w.x + qq[i * 4 + 1] * w.y +
               qq[i * 4 + 2] * w.z + qq[i * 4 + 3] * w.w;
    }
    acc += __shfl_xor(acc, 1, 64);
    acc += __shfl_xor(acc, 2, 64);
    if (quarter == 0) qp[b * H + n] = acc + Wab[n] + Uab[n];
}

// ---------------------------------------------------------------------------
// K2v3: barrier-free streaming GEMM, 4-deep explicit register pipeline.
// Block = 128 rows x 128 n (one nb). 4 waves: wave wm owns 2 m-tiles x 8 n-tiles.
// 4 fragment buffer sets (fa/fb[p]); per group: 16 MFMA on set p, then issue
// set p's 10 coalesced 16B loads for kc+4 (issue->use distance = 3 MFMA groups
// ~230 cy/wave, x2 waves/SIMD ~460 cy coverage -> hides L2/L3 latency).
// Tail prefetch indices clamped with &31 (redundant valid loads, branch-free).
// No LDS, no __syncthreads in the K-loop. Per-nb partials stored directly.
__global__ __launch_bounds__(256, 2) void k2_scores2(
    const uint4* __restrict__ Abf, const uint4* __restrict__ UaSw,
    const float* __restrict__ qp, const float* __restrict__ Vaw,
    float* __restrict__ sp) {
    const int tid = threadIdx.x;
    const int lane = tid & 63;
    const int wm = tid >> 6;
    const int lid = blockIdx.x;      // 0..4095
    const int c = lid & 7;           // XCD slot (round-robin by linear id)
    const int qq = lid >> 3;
    const int nb = qq & 7;           // nb cycles fastest within an XCD
    const int mb = (qq >> 3) * 8 + c;
    const int b = mb >> 4;
    const int s0 = (mb & 15) << 7;

    const int stile0 = mb * 8 + wm * 2;
    const uint4* pa = Abf + (size_t)stile0 * 2048 + lane;   // kc stride 64, mt stride 2048
    const uint4* pb = UaSw + (size_t)nb * 16384 + lane;     // kc stride 512, nt stride 64

    f32x4 acc[2][8];
#pragma unroll
    for (int mt = 0; mt < 2; mt++)
#pragma unroll
        for (int nt = 0; nt < 8; nt++) acc[mt][nt] = (f32x4){0.f, 0.f, 0.f, 0.f};

    // 4 explicit buffer sets -> compiler cannot collapse the pipeline.
    U4 fa[4][2], fb[4][8];
#pragma unroll
    for (int p = 0; p < 4; p++) {
        fa[p][0].u = pa[p * 64];
        fa[p][1].u = pa[p * 64 + 2048];
#pragma unroll
        for (int nt = 0; nt < 8; nt++) fb[p][nt].u = pb[p * 512 + nt * 64];
    }

    for (int kc = 0; kc < 32; kc += 4) {
#pragma unroll
        for (int p = 0; p < 4; p++) {
#pragma unroll
            for (int nt = 0; nt < 8; nt++)
#pragma unroll
                for (int mt = 0; mt < 2; mt++)
                    acc[mt][nt] = __builtin_amdgcn_mfma_f32_16x16x32_bf16(
                        fa[p][mt].b, fb[p][nt].b, acc[mt][nt], 0, 0, 0);
            const int kn = (kc + 4 + p) & 31;   // tail: redundant reload of kc 0..3
            fa[p][0].u = pa[kn * 64];
            fa[p][1].u = pa[kn * 64 + 2048];
#pragma unroll
            for (int nt = 0; nt < 8; nt++) fb[p][nt].u = pb[kn * 512 + nt * 64];
        }
    }

    // epilogue: tanh, dot Va, shfl-reduce over col(16), direct store (disjoint rows)
    const int col = lane & 15, qd = lane >> 4;
    float qv[8], vv[8];
#pragma unroll
    for (int nt = 0; nt < 8; nt++) {
        int n = nb * 128 + nt * 16 + col;
        qv[nt] = qp[b * H + n];
        vv[nt] = Vaw[n];
    }
#pragma unroll
    for (int mt = 0; mt < 2; mt++) {
        float rs[4] = {0.f, 0.f, 0.f, 0.f};
#pragma unroll
        for (int nt = 0; nt < 8; nt++)
#pragma unroll
            for (int r = 0; r < 4; r++)
                rs[r] += ftanh(acc[mt][nt][r] + qv[nt]) * vv[nt];
#pragma unroll
        for (int r = 0; r < 4; r++) {
            float v = rs[r];
            v += __shfl_xor(v, 1, 64);
            v += __shfl_xor(v, 2, 64);
            v += __shfl_xor(v, 4, 64);
            v += __shfl_xor(v, 8, 64);
            if (col == 0)
                sp[(size_t)nb * B * S + b * S + s0 + wm * 32 + mt * 16 + qd * 4 + r] = v;
        }
    }
}

// ---------------------------------------------------------------------------
// K4v2: fused partial-sum + softmax + weights-write + context from bf16 keys.
// grid (8,32): block (kcg,b); wave wv handles kc=kcg*4+wv. Each (b,kc,q,j)
// owns unique context cols -> plain stores, no pre-zero needed.
__global__ __launch_bounds__(256) void k4_ctx2(const uint4* __restrict__ Abf,
                                               const float* __restrict__ sp,
                                               float* __restrict__ out) {
    int kcg = blockIdx.x, b = blockIdx.y;
    int t = threadIdx.x;
    __shared__ float red[256];
    __shared__ float wl[S];   // 8 KB

    float v[8];
#pragma unroll
    for (int i = 0; i < 8; i++) {
        int s = i * 256 + t;
        float sum = 0.f;
#pragma unroll
        for (int nb = 0; nb < 8; nb++) sum += sp[(size_t)nb * B * S + b * S + s];
        v[i] = sum;
    }
    float lm = -1e30f;
#pragma unroll
    for (int i = 0; i < 8; i++) lm = fmaxf(lm, v[i]);
    red[t] = lm;
    __syncthreads();
    for (int s = 128; s > 0; s >>= 1) {
        if (t < s) red[t] = fmaxf(red[t], red[t + s]);
        __syncthreads();
    }
    float m = red[0];
    __syncthreads();
    float ls = 0.f;
#pragma unroll
    for (int i = 0; i < 8; i++) ls += __expf(v[i] - m);
    red[t] = ls;
    __syncthreads();
    for (int s = 128; s > 0; s >>= 1) {
        if (t < s) red[t] += red[t + s];
        __syncthreads();
    }
    float inv = 1.f / red[0];
#pragma unroll
    for (int i = 0; i < 8; i++) {
        int s = i * 256 + t;
        float w = __expf(v[i] - m) * inv;
        wl[s] = w;
        if (kcg == 0) out[B * H + b * S + s] = w;
    }
    __syncthreads();

    const int wv = t >> 6, lane = t & 63, qd = lane >> 4, colr = lane & 15;
    const int kc = kcg * 4 + wv;
    float a8[8] = {0.f, 0.f, 0.f, 0.f, 0.f, 0.f, 0.f, 0.f};
    const uint4* base = Abf + ((size_t)(b * 128) * 32 + kc) * 64 + lane;
#pragma unroll 4
    for (int st = 0; st < 128; st++) {
        uint4 f = base[(size_t)st * 2048];
        float w = wl[st * 16 + colr];
        a8[0] += w * __uint_as_float(f.x << 16);
        a8[1] += w * __uint_as_float(f.x & 0xffff0000u);
        a8[2] += w * __uint_as_float(f.y << 16);
        a8[3] += w * __uint_as_float(f.y & 0xffff0000u);
        a8[4] += w * __uint_as_float(f.z << 16);
        a8[5] += w * __uint_as_float(f.z & 0xffff0000u);
        a8[6] += w * __uint_as_float(f.w << 16);
        a8[7] += w * __uint_as_float(f.w & 0xffff0000u);
    }
#pragma unroll
    for (int j = 0; j < 8; j++) {
        float vj = a8[j];
        vj += __shfl_xor(vj, 1, 64);
        vj += __shfl_xor(vj, 2, 64);
        vj += __shfl_xor(vj, 4, 64);
        vj += __shfl_xor(vj, 8, 64);
        a8[j] = vj;
    }
    if (colr == 0) {
        int colbase = kc * 32 + qd * 8;
#pragma unroll
        for (int j = 0; j < 8; j++) out[b * H + colbase + j] = a8[j];
    }
}

// ===========================================================================
// Fallback path (ws too small): round-4 kernels
// ===========================================================================
__global__ __launch_bounds__(256, 3) void k2_scores_fb(
    const float* __restrict__ keys, const uint4* __restrict__ UaSw,
    const float* __restrict__ qp, const float* __restrict__ Vaw,
    float* __restrict__ sp) {
    __shared__ uint4 As[2][512];
    __shared__ uint4 Bs[2][512];
    __shared__ float part[2][128];
    const int tid = threadIdx.x;
    const int lane = tid & 63;
    const int wave = tid >> 6;
    const int wm = wave >> 1, wn = wave & 1;
    const int lid = blockIdx.x;
    const int c = lid & 7;
    const int qq = lid >> 3;
    const int nb = qq & 7;
    const int mb = (qq >> 3) * 8 + c;
    const int b = mb >> 4;
    const int s0 = (mb & 15) << 7;
    const int el = tid & 63;
    const int srow0 = s0 + (tid >> 6) * 16 + (el & 15);
    const int srow1 = srow0 + 64;
    const int kofs = ((el >> 4) & 3) * 8;
    const float4* ka0 = (const float4*)(keys + ((size_t)b * S + srow0) * H + kofs);
    const float4* ka1 = (const float4*)(keys + ((size_t)b * S + srow1) * H + kofs);
    const uint4* srcB = UaSw + (size_t)nb * 32 * 512;
    f32x4 acc[4][4];
#pragma unroll
    for (int mt = 0; mt < 4; mt++)
#pragma unroll
        for (int nt = 0; nt < 4; nt++) acc[mt][nt] = (f32x4){0.f, 0.f, 0.f, 0.f};
    float4 x0 = ka0[0], y0 = ka0[1], x1 = ka1[0], y1 = ka1[1];
    async_copy16(srcB + tid,       &Bs[0][tid]);
    async_copy16(srcB + tid + 256, &Bs[0][tid + 256]);
    As[0][tid]       = pack8(x0, y0);
    As[0][tid + 256] = pack8(x1, y1);
    x0 = ka0[8]; y0 = ka0[9]; x1 = ka1[8]; y1 = ka1[9];
    __syncthreads();
    for (int kc = 0; kc < 32; kc++) {
        const int cur = kc & 1, nxt = cur ^ 1;
        if (kc < 31) {
            async_copy16(srcB + (size_t)(kc + 1) * 512 + tid,       &Bs[nxt][tid]);
            async_copy16(srcB + (size_t)(kc + 1) * 512 + tid + 256, &Bs[nxt][tid + 256]);
            As[nxt][tid]       = pack8(x0, y0);
            As[nxt][tid + 256] = pack8(x1, y1);
            if (kc < 30) {
                x0 = ka0[(kc + 2) * 8]; y0 = ka0[(kc + 2) * 8 + 1];
                x1 = ka1[(kc + 2) * 8]; y1 = ka1[(kc + 2) * 8 + 1];
            }
        }
        U4 af[4], bf[4];
#pragma unroll
        for (int mt = 0; mt < 4; mt++) af[mt].u = As[cur][(wm * 4 + mt) * 64 + lane];
#pragma unroll
        for (int nt = 0; nt < 4; nt++) bf[nt].u = Bs[cur][(wn * 4 + nt) * 64 + lane];
#pragma unroll
        for (int mt = 0; mt < 4; mt++)
#pragma unroll
            for (int nt = 0; nt < 4; nt++)
                acc[mt][nt] = __builtin_amdgcn_mfma_f32_16x16x32_bf16(
                    af[mt].b, bf[nt].b, acc[mt][nt], 0, 0, 0);
        __syncthreads();
    }
    const int col = lane & 15, qd = lane >> 4;
    float qv[4], vv[4];
#pragma unroll
    for (int nt = 0; nt < 4; nt++) {
        int n = nb * 128 + (wn * 4 + nt) * 16 + col;
        qv[nt] = qp[b * H + n];
        vv[nt] = Vaw[n];
    }
#pragma unroll
    for (int mt = 0; mt < 4; mt++) {
        float rs[4] = {0.f, 0.f, 0.f, 0.f};
#pragma unroll
        for (int nt = 0; nt < 4; nt++)
#pragma unroll
            for (int r = 0; r < 4; r++)
                rs[r] += ftanh(acc[mt][nt][r] + qv[nt]) * vv[nt];
#pragma unroll
        for (int r = 0; r < 4; r++) {
            float v = rs[r];
            v += __shfl_xor(v, 1, 64);
            v += __shfl_xor(v, 2, 64);
            v += __shfl_xor(v, 4, 64);
            v += __shfl_xor(v, 8, 64);
            if (col == 0) part[wn][wm * 64 + mt * 16 + qd * 4 + r] = v;
        }
    }
    __syncthreads();
    if (tid < 128)
        sp[(size_t)nb * B * S + b * S + s0 + tid] = part[0][tid] + part[1][tid];
}

__global__ __launch_bounds__(256) void k4_ctx_fb(const float* __restrict__ keys,
                                                 const float* __restrict__ sp,
                                                 float* __restrict__ out) {
    int sc = blockIdx.x, b = blockIdx.y;
    int t = threadIdx.x;
    __shared__ float red[256];
    __shared__ float wl[64];
    float v[8];
#pragma unroll
    for (int i = 0; i < 8; i++) {
        int s = i * 256 + t;
        float sum = 0.f;
#pragma unroll
        for (int nb = 0; nb < 8; nb++) sum += sp[(size_t)nb * B * S + b * S + s];
        v[i] = sum;
    }
    float lm = -1e30f;
#pragma unroll
    for (int i = 0; i < 8; i++) lm = fmaxf(lm, v[i]);
    red[t] = lm;
    __syncthreads();
    for (int s = 128; s > 0; s >>= 1) {
        if (t < s) red[t] = fmaxf(red[t], red[t + s]);
        __syncthreads();
    }
    float m = red[0];
    __syncthreads();
    float ls = 0.f;
#pragma unroll
    for (int i = 0; i < 8; i++) ls += __expf(v[i] - m);
    red[t] = ls;
    __syncthreads();
    for (int s = 128; s > 0; s >>= 1) {
        if (t < s) red[t] += red[t + s];
        __syncthreads();
    }
    float inv = 1.f / red[0];
    if (t < 64) {
        int s = sc * 64 + t;
        float sum = 0.f;
#pragma unroll
        for (int nb = 0; nb < 8; nb++) sum += sp[(size_t)nb * B * S + b * S + s];
        float w = __expf(sum - m) * inv;
        wl[t] = w;
        out[B * H + b * S + s] = w;
    }
    __syncthreads();
    const float4* kp = (const float4*)(keys + ((size_t)b * S + sc * 64) * H) + t;
    float4 acc = {0.f, 0.f, 0.f, 0.f};
#pragma unroll 8
    for (int s = 0; s < 64; s++) {
        float4 kv = kp[(size_t)s * 256];
        float w = wl[s];
        acc.x += w * kv.x; acc.y += w * kv.y;
        acc.z += w * kv.z; acc.w += w * kv.w;
    }
    float* dst = out + b * H + t * 4;
    atomicAdd(dst + 0, acc.x);
    atomicAdd(dst + 1, acc.y);
    atomicAdd(dst + 2, acc.z);
    atomicAdd(dst + 3, acc.w);
}

// ---------------------------------------------------------------------------
extern "C" void kernel_launch(void* const* d_in, const int* in_sizes, int n_in,
                              void* d_out, int out_size, void* d_ws, size_t ws_size,
                              hipStream_t stream) {
    const float* query = (const float*)d_in[0];
    const float* keys  = (const float*)d_in[1];
    const float* Wa_w  = (const float*)d_in[2];
    const float* Wa_b  = (const float*)d_in[3];
    const float* Ua_w  = (const float*)d_in[4];
    const float* Ua_b  = (const float*)d_in[5];
    const float* Va_w  = (const float*)d_in[6];
    float* out = (float*)d_out;

    // ws: [0,2MB) UaSw; [2MB,+128KB) qp; [2MB+128KB,+2MB) sp; [8MB,+128MB) Abf
    uint4* UaSw = (uint4*)d_ws;
    float* qp = (float*)((char*)d_ws + (2u << 20));
    float* sp = (float*)((char*)d_ws + (2u << 20) + (128u << 10));
    uint4* Abf = (uint4*)((char*)d_ws + (8u << 20));
    const size_t NEED = (size_t)(8u << 20) + ((size_t)128u << 20);

    if (ws_size >= NEED) {
        ka_swz<<<32768, 256, 0, stream>>>(keys, Abf);
        k0_swizzle<<<512, 256, 0, stream>>>(Ua_w, UaSw);
        k1_qproj<<<dim3(16, B), 256, 0, stream>>>(query, Wa_w, Wa_b, Ua_b, qp);
        k2_scores2<<<4096, 256, 0, stream>>>(Abf, UaSw, qp, Va_w, sp);
        k4_ctx2<<<dim3(8, B), 256, 0, stream>>>(Abf, sp, out);
    } else {
        hipMemsetAsync(d_out, 0, B * H * sizeof(float), stream);
        k0_swizzle<<<512, 256, 0, stream>>>(Ua_w, UaSw);
        k1_qproj<<<dim3(16, B), 256, 0, stream>>>(query, Wa_w, Wa_b, Ua_b, qp);
        k2_scores_fb<<<4096, 256, 0, stream>>>(keys, UaSw, qp, Va_w, sp);
        k4_ctx_fb<<<dim3(32, B), 256, 0, stream>>>(keys, sp, out);
    }
}